// Round 8
// baseline (227.556 us; speedup 1.0000x reference)
//
#include <hip/hip_runtime.h>
#include <hip/hip_bf16.h>

#define SEQ 2048
#define DM 1024
#define NB 4

typedef short bf16x8 __attribute__((ext_vector_type(8)));
typedef float f32x4 __attribute__((ext_vector_type(4)));
typedef float f32x4v __attribute__((ext_vector_type(4)));
typedef unsigned short u16x4 __attribute__((ext_vector_type(4)));
typedef unsigned short u16x8 __attribute__((ext_vector_type(8)));

__device__ __forceinline__ float bf2f(unsigned short u) {
  union { unsigned int i; float f; } w; w.i = ((unsigned int)u) << 16; return w.f;
}
__device__ __forceinline__ unsigned short f2bf(float f) {
  union { __hip_bfloat16 h; unsigned short u; } w; w.h = __float2bfloat16(f); return w.u;
}
__device__ __forceinline__ void load_lds16(const void* g, void* l) {
  __builtin_amdgcn_global_load_lds((const __attribute__((address_space(1))) void*)g,
                                   (__attribute__((address_space(3))) void*)l, 16, 0, 0);
}
__device__ __forceinline__ void cvt4(const float* __restrict__ in,
                                     unsigned short* __restrict__ out, int i) {
  f32x4v v = ((const f32x4v*)in)[i];
  u16x4 o;
  o[0] = f2bf(v[0]); o[1] = f2bf(v[1]); o[2] = f2bf(v[2]); o[3] = f2bf(v[3]);
  ((u16x4*)out)[i] = o;
}

// One fused staging pass: x->xb, {wq,wk,wv}->wqkvb, lin_w->lwb, biases->bqkv (f32 concat).
__global__ __launch_bounds__(256) void stage_kernel(
    const float* __restrict__ x,
    const float* __restrict__ wq, const float* __restrict__ wk,
    const float* __restrict__ wv, const float* __restrict__ lw,
    const float* __restrict__ bq, const float* __restrict__ bk, const float* __restrict__ bv,
    unsigned short* __restrict__ xb, unsigned short* __restrict__ wqkvb,
    unsigned short* __restrict__ lwb, float* __restrict__ bqkv)
{
  const int XC = (NB * SEQ * DM) / 4;
  const int WC = (DM * DM) / 4;
  const int BC = (3 * DM) / 4;
  const int total = XC + 4 * WC + BC;
  int idx = blockIdx.x * 256 + threadIdx.x;
  int stride = gridDim.x * 256;
  for (int i = idx; i < total; i += stride) {
    if (i < XC) { cvt4(x, xb, i); continue; }
    int j = i - XC;
    if (j < WC)          { cvt4(wq, wqkvb, j); continue; }
    if (j < 2 * WC)      { cvt4(wk, wqkvb + (size_t)DM * DM, j - WC); continue; }
    if (j < 3 * WC)      { cvt4(wv, wqkvb + 2 * (size_t)DM * DM, j - 2 * WC); continue; }
    if (j < 4 * WC)      { cvt4(lw, lwb, j - 3 * WC); continue; }
    int c = j - 4 * WC;
    const float* src = (c < 256) ? bq : ((c < 512) ? bk : bv);
    int off = (c < 256) ? c : ((c < 512) ? c - 256 : c - 512);
    ((f32x4v*)bqkv)[c] = ((const f32x4v*)src)[off];
  }
}

// ---------------- 128x128 / BK=64 / 4-wave GEMM (m97 structure) ----------------
// C = A * B^T (+bias) (*scale).
// __launch_bounds__(256,4): 4 blocks/CU (was 2 — R6 Occupancy=30% showed the cap;
// m114: cross-block wave overlap is what hides the barrier drain).
// Bijective XCD swizzle on the flat block id (all grids used are %8==0).
// trilskip: skip blocks fully above output diagonal (masked downstream).
// vtOut/vtBase: blocks with n0 >= vtBase write output TRANSPOSED into vtOut[NB][DM][SEQ].
__global__ __launch_bounds__(256, 4) void gemm_bt(
    const unsigned short* __restrict__ A, int lda, long sA,
    const unsigned short* __restrict__ B, int ldb, long sB,
    void* __restrict__ Cv, int ldc, long sC,
    int K, const float* __restrict__ bias, float scale, int outf32, int trilskip,
    unsigned short* __restrict__ vtOut, int vtBase)
{
  // XCD-aware remap: hardware round-robins flat id across 8 XCDs; give each XCD
  // a contiguous chunk of the work-id space instead.
  const int gx = gridDim.x, gy = gridDim.y;
  int flat = (blockIdx.z * gy + blockIdx.y) * gx + blockIdx.x;
  const int nwg = gx * gy * gridDim.z;
  const int cpx = nwg >> 3;
  int swz = (flat & 7) * cpx + (flat >> 3);
  const int bx = swz % gx;
  int rem = swz / gx;
  const int by = rem % gy;
  const int bz = rem / gy;

  const int m0 = bx * 128, n0 = by * 128;
  if (trilskip && n0 > m0 + 127) return;
  __shared__ unsigned short As[128 * 64];
  __shared__ unsigned short Bs[128 * 64];
  const int tid = threadIdx.x;
  const int lane = tid & 63;
  const int wave = tid >> 6;
  const int wm = wave >> 1, wn = wave & 1;
  const unsigned short* Ab = A + (size_t)sA * bz;
  const unsigned short* Bb = B + (size_t)sB * bz;

  f32x4 acc[4][4];
#pragma unroll
  for (int i = 0; i < 4; ++i)
#pragma unroll
    for (int j = 0; j < 4; ++j)
      acc[i][j] = (f32x4){0.f, 0.f, 0.f, 0.f};

  const int nk = K >> 6;
  for (int kt = 0; kt < nk; ++kt) {
    __syncthreads();
    const int kb = kt << 6;
#pragma unroll
    for (int it = 0; it < 4; ++it) {
      int c = it * 256 + tid;
      int row = c >> 3;
      int lslot = (c & 7) ^ (row & 7);
      int ldsoff = (it * 256 + wave * 64) * 8;
      load_lds16(Ab + (size_t)(m0 + row) * lda + kb + lslot * 8, &As[ldsoff]);
      load_lds16(Bb + (size_t)(n0 + row) * ldb + kb + lslot * 8, &Bs[ldsoff]);
    }
    __syncthreads();
#pragma unroll
    for (int h = 0; h < 2; ++h) {
      bf16x8 af[4], bfr[4];
#pragma unroll
      for (int i = 0; i < 4; ++i) {
        int row = wm * 64 + i * 16 + (lane & 15);
        int pslot = (h * 4 + (lane >> 4)) ^ (row & 7);
        af[i] = *(const bf16x8*)&As[row * 64 + pslot * 8];
      }
#pragma unroll
      for (int j = 0; j < 4; ++j) {
        int row = wn * 64 + j * 16 + (lane & 15);
        int pslot = (h * 4 + (lane >> 4)) ^ (row & 7);
        bfr[j] = *(const bf16x8*)&Bs[row * 64 + pslot * 8];
      }
#pragma unroll
      for (int i = 0; i < 4; ++i)
#pragma unroll
        for (int j = 0; j < 4; ++j)
          acc[i][j] = __builtin_amdgcn_mfma_f32_16x16x32_bf16(af[i], bfr[j], acc[i][j], 0, 0, 0);
    }
  }

  // C/D layout: col = lane&15, row = (lane>>4)*4 + reg
  const int rsub = (lane >> 4) * 4;
  const int cbase = n0 + wn * 64 + (lane & 15);
  if (vtOut && n0 >= vtBase) {
    float bv[4] = {0.f, 0.f, 0.f, 0.f};
    if (bias) {
#pragma unroll
      for (int j = 0; j < 4; ++j) bv[j] = bias[cbase + j * 16];
    }
#pragma unroll
    for (int i = 0; i < 4; ++i) {
      int sg = m0 + wm * 64 + i * 16 + rsub;   // global row = batch*SEQ + s
      int bb = sg >> 11;
      int sl = sg & (SEQ - 1);
#pragma unroll
      for (int j = 0; j < 4; ++j) {
        int d = cbase + j * 16 - vtBase;
        u16x4 o;
#pragma unroll
        for (int r = 0; r < 4; ++r) o[r] = f2bf(acc[i][j][r] * scale + bv[j]);
        *(u16x4*)&vtOut[((size_t)bb * DM + d) * SEQ + sl] = o;
      }
    }
  } else if (outf32) {
    float* C = (float*)Cv + (size_t)sC * bz;
#pragma unroll
    for (int i = 0; i < 4; ++i) {
      int rbase = m0 + wm * 64 + i * 16 + rsub;
#pragma unroll
      for (int j = 0; j < 4; ++j)
#pragma unroll
        for (int r = 0; r < 4; ++r)
          C[(size_t)(rbase + r) * ldc + cbase + j * 16] = acc[i][j][r] * scale;
    }
  } else {
    unsigned short* C = (unsigned short*)Cv + (size_t)sC * bz;
    float bv[4] = {0.f, 0.f, 0.f, 0.f};
    if (bias) {
#pragma unroll
      for (int j = 0; j < 4; ++j) bv[j] = bias[cbase + j * 16];
    }
#pragma unroll
    for (int i = 0; i < 4; ++i) {
      int rbase = m0 + wm * 64 + i * 16 + rsub;
#pragma unroll
      for (int j = 0; j < 4; ++j)
#pragma unroll
        for (int r = 0; r < 4; ++r)
          C[(size_t)(rbase + r) * ldc + cbase + j * 16] = f2bf(acc[i][j][r] * scale + bv[j]);
    }
  }
}

// in-place row softmax over SEQ bf16 -> bf16 probs. one block per row.
__global__ __launch_bounds__(256) void softmax_kernel(unsigned short* __restrict__ Sc) {
  int row = blockIdx.x;
  int tid = threadIdx.x;
  unsigned short* sr = Sc + (size_t)row * SEQ;
  u16x8 raw = *(const u16x8*)&sr[tid * 8];
  float v[8];
#pragma unroll
  for (int j = 0; j < 8; ++j) v[j] = bf2f(raw[j]);
  float m = v[0];
#pragma unroll
  for (int j = 1; j < 8; ++j) m = fmaxf(m, v[j]);
#pragma unroll
  for (int off = 32; off; off >>= 1) m = fmaxf(m, __shfl_xor(m, off));
  __shared__ float red[8];
  int wv = tid >> 6;
  if ((tid & 63) == 0) red[wv] = m;
  __syncthreads();
  m = fmaxf(fmaxf(red[0], red[1]), fmaxf(red[2], red[3]));
  float s = 0.f;
#pragma unroll
  for (int j = 0; j < 8; ++j) { v[j] = __expf(v[j] - m); s += v[j]; }
#pragma unroll
  for (int off = 32; off; off >>= 1) s += __shfl_xor(s, off);
  if ((tid & 63) == 0) red[4 + wv] = s;
  __syncthreads();
  s = red[4] + red[5] + red[6] + red[7];
  float inv = 1.f / s;
  u16x8 o;
#pragma unroll
  for (int j = 0; j < 8; ++j) o[j] = f2bf(v[j] * inv);
  *(u16x8*)&sr[tid * 8] = o;
}

// y = LN(x + res(masked)) * g + b. x from f32 (xf) or bf16 (xb); out f32 or bf16.
__global__ __launch_bounds__(256) void ln_kernel(
    const float* __restrict__ xf, const unsigned short* __restrict__ xb,
    const unsigned short* __restrict__ res, int masked,
    const float* __restrict__ g, const float* __restrict__ be,
    float* __restrict__ outf, unsigned short* __restrict__ outb)
{
  int row = blockIdx.x;
  int s = row & (SEQ - 1);
  int tid = threadIdx.x;
  int d0 = tid * 4;
  float v[4];
  if (xf) {
    f32x4v t = ((const f32x4v*)(xf + (size_t)row * DM))[tid];
    v[0]=t[0]; v[1]=t[1]; v[2]=t[2]; v[3]=t[3];
  } else {
    u16x4 t = ((const u16x4*)(xb + (size_t)row * DM))[tid];
    v[0]=bf2f(t[0]); v[1]=bf2f(t[1]); v[2]=bf2f(t[2]); v[3]=bf2f(t[3]);
  }
  u16x4 rv = ((const u16x4*)(res + (size_t)row * DM))[tid];
#pragma unroll
  for (int j = 0; j < 4; ++j) {
    float r = bf2f(rv[j]);
    if (masked && (d0 + j) > s) r = 0.f;
    v[j] += r;
  }
  float s1 = v[0] + v[1] + v[2] + v[3];
  float s2 = v[0]*v[0] + v[1]*v[1] + v[2]*v[2] + v[3]*v[3];
#pragma unroll
  for (int off = 32; off; off >>= 1) { s1 += __shfl_xor(s1, off); s2 += __shfl_xor(s2, off); }
  __shared__ float red[8];
  int wv = tid >> 6;
  if ((tid & 63) == 0) { red[wv] = s1; red[4 + wv] = s2; }
  __syncthreads();
  s1 = red[0] + red[1] + red[2] + red[3];
  s2 = red[4] + red[5] + red[6] + red[7];
  float mean = s1 * (1.f / DM);
  float var = s2 * (1.f / DM) - mean * mean;
  float rstd = rsqrtf(var + 1e-5f);
  f32x4v gv = ((const f32x4v*)g)[tid];
  f32x4v bv = ((const f32x4v*)be)[tid];
  if (outf) {
    f32x4v o;
#pragma unroll
    for (int j = 0; j < 4; ++j) o[j] = (v[j] - mean) * rstd * gv[j] + bv[j];
    ((f32x4v*)(outf + (size_t)row * DM))[tid] = o;
  } else {
    u16x4 o;
#pragma unroll
    for (int j = 0; j < 4; ++j) o[j] = f2bf((v[j] - mean) * rstd * gv[j] + bv[j]);
    ((u16x4*)(outb + (size_t)row * DM))[tid] = o;
  }
}

extern "C" void kernel_launch(void* const* d_in, const int* in_sizes, int n_in,
                              void* d_out, int out_size, void* d_ws, size_t ws_size,
                              hipStream_t stream) {
  (void)in_sizes; (void)n_in; (void)out_size; (void)ws_size;
  const float* x     = (const float*)d_in[0];
  const float* wq_w  = (const float*)d_in[1];
  const float* wq_b  = (const float*)d_in[2];
  const float* wk_w  = (const float*)d_in[3];
  const float* wk_b  = (const float*)d_in[4];
  const float* wv_w  = (const float*)d_in[5];
  const float* wv_b  = (const float*)d_in[6];
  const float* lin_w = (const float*)d_in[7];
  const float* lin_b = (const float*)d_in[8];
  const float* g1    = (const float*)d_in[9];
  const float* b1    = (const float*)d_in[10];
  const float* g2    = (const float*)d_in[11];
  const float* b2    = (const float*)d_in[12];

  const size_t MB = 1ull << 20;
  char* ws = (char*)d_ws;
  // ---- workspace layout: NO overlays (peak 176 MiB) ----
  unsigned short* scP  = (unsigned short*)(ws);            // [0,32)   scores/probs bf16, in-place softmax
  unsigned short* attn = (unsigned short*)(ws + 32*MB);    // [32,48)
  unsigned short* x1   = (unsigned short*)(ws + 48*MB);    // [48,64)
  unsigned short* lin  = (unsigned short*)(ws + 64*MB);    // [64,80)
  unsigned short* xb   = (unsigned short*)(ws + 80*MB);    // [80,96)
  unsigned short* wqkvb= (unsigned short*)(ws + 96*MB);    // [96,102)
  unsigned short* lwb  = (unsigned short*)(ws + 102*MB);   // [102,104)
  float*          bqkv = (float*)(ws + 104*MB);            // [104,+12KiB)
  unsigned short* qkv  = (unsigned short*)(ws + 112*MB);   // [112,160)  (V cols unwritten/unused)
  unsigned short* vt   = (unsigned short*)(ws + 160*MB);   // [160,176)  V^T [NB][DM][SEQ]

  // 1. fused staging
  stage_kernel<<<2048, 256, 0, stream>>>(x, wq_w, wk_w, wv_w, lin_w, wq_b, wk_b, wv_b,
                                         xb, wqkvb, lwb, bqkv);

  // 2. fused QKV projection (64x24 = 1536 blocks, now 4/CU); V blocks (n0>=2048) write V^T directly
  gemm_bt<<<dim3(64, 24, 1), 256, 0, stream>>>(xb, DM, 0, wqkvb, DM, 0, qkv, 3 * DM, 0,
                                               DM, bqkv, 1.f, 0, 0, vt, 2 * DM);

  const float scale = 0.03125f;  // 1/sqrt(1024)
  // 3. scores = (Q K^T) * scale -> bf16 (16x16x4 = 1024 blocks)
  gemm_bt<<<dim3(16, 16, NB), 256, 0, stream>>>(
      qkv, 3 * DM, (long)SEQ * 3 * DM,
      qkv + DM, 3 * DM, (long)SEQ * 3 * DM,
      scP, SEQ, (long)SEQ * SEQ, DM, nullptr, scale, 0, 0, nullptr, 0);
  // 4. softmax in-place
  softmax_kernel<<<NB * SEQ, 256, 0, stream>>>(scP);
  // 5. attn = P * (V^T)^T with tril tile-skip
  gemm_bt<<<dim3(16, 8, NB), 256, 0, stream>>>(
      scP, SEQ, (long)SEQ * SEQ,
      vt, SEQ, (long)DM * SEQ,
      attn, DM, (long)SEQ * DM, SEQ, nullptr, 1.f, 0, 1, nullptr, 0);

  // 6. LN1(xb + tril(attn)) -> x1 (bf16)
  ln_kernel<<<NB * SEQ, 256, 0, stream>>>(nullptr, xb, attn, 1, g1, b1, nullptr, x1);
  // 7. linear = x1 * lin_w^T + lin_b  (512 blocks)
  gemm_bt<<<dim3(64, 8, 1), 256, 0, stream>>>(x1, DM, 0, lwb, DM, 0, lin, DM, 0, DM,
                                              lin_b, 1.f, 0, 0, nullptr, 0);
  // 8. LN2(x1 + linear) -> d_out (f32)
  ln_kernel<<<NB * SEQ, 256, 0, stream>>>(nullptr, x1, lin, 0, g2, b2, (float*)d_out, nullptr);
}

// Round 9
// 208.959 us; speedup vs baseline: 1.0890x; 1.0890x over previous
//
#include <hip/hip_runtime.h>
#include <hip/hip_bf16.h>

#define SEQ 2048
#define DM 1024
#define NB 4

typedef short bf16x8 __attribute__((ext_vector_type(8)));
typedef float f32x4 __attribute__((ext_vector_type(4)));
typedef float f32x4v __attribute__((ext_vector_type(4)));
typedef unsigned short u16x4 __attribute__((ext_vector_type(4)));
typedef unsigned short u16x8 __attribute__((ext_vector_type(8)));

__device__ __forceinline__ float bf2f(unsigned short u) {
  union { unsigned int i; float f; } w; w.i = ((unsigned int)u) << 16; return w.f;
}
__device__ __forceinline__ unsigned short f2bf(float f) {
  union { __hip_bfloat16 h; unsigned short u; } w; w.h = __float2bfloat16(f); return w.u;
}
__device__ __forceinline__ void load_lds16(const void* g, void* l) {
  __builtin_amdgcn_global_load_lds((const __attribute__((address_space(1))) void*)g,
                                   (__attribute__((address_space(3))) void*)l, 16, 0, 0);
}
__device__ __forceinline__ void cvt4(const float* __restrict__ in,
                                     unsigned short* __restrict__ out, int i) {
  f32x4v v = ((const f32x4v*)in)[i];
  u16x4 o;
  o[0] = f2bf(v[0]); o[1] = f2bf(v[1]); o[2] = f2bf(v[2]); o[3] = f2bf(v[3]);
  ((u16x4*)out)[i] = o;
}

// One fused staging pass: x->xb, {wq,wk,wv}->wqkvb, lin_w->lwb, biases->bqkv (f32 concat).
__global__ __launch_bounds__(256) void stage_kernel(
    const float* __restrict__ x,
    const float* __restrict__ wq, const float* __restrict__ wk,
    const float* __restrict__ wv, const float* __restrict__ lw,
    const float* __restrict__ bq, const float* __restrict__ bk, const float* __restrict__ bv,
    unsigned short* __restrict__ xb, unsigned short* __restrict__ wqkvb,
    unsigned short* __restrict__ lwb, float* __restrict__ bqkv)
{
  const int XC = (NB * SEQ * DM) / 4;
  const int WC = (DM * DM) / 4;
  const int BC = (3 * DM) / 4;
  const int total = XC + 4 * WC + BC;
  int idx = blockIdx.x * 256 + threadIdx.x;
  int stride = gridDim.x * 256;
  for (int i = idx; i < total; i += stride) {
    if (i < XC) { cvt4(x, xb, i); continue; }
    int j = i - XC;
    if (j < WC)          { cvt4(wq, wqkvb, j); continue; }
    if (j < 2 * WC)      { cvt4(wk, wqkvb + (size_t)DM * DM, j - WC); continue; }
    if (j < 3 * WC)      { cvt4(wv, wqkvb + 2 * (size_t)DM * DM, j - 2 * WC); continue; }
    if (j < 4 * WC)      { cvt4(lw, lwb, j - 3 * WC); continue; }
    int c = j - 4 * WC;
    const float* src = (c < 256) ? bq : ((c < 512) ? bk : bv);
    int off = (c < 256) ? c : ((c < 512) ? c - 256 : c - 512);
    ((f32x4v*)bqkv)[c] = ((const f32x4v*)src)[off];
  }
}

// ---------------- 128x128 / BK=64 / 4-wave GEMM (m97 structure, ~950 TF here) ----
// C = A * B^T (+bias) (*scale). Natural block mapping (R8 lesson: with gx%8==0 the
// HW round-robin already gives each XCD a fixed 2MB A-panel that L2-fits; a
// "contiguous chunk" XCD swizzle makes every XCD stream ALL of A -> 8x over-fetch).
// trilskip: skip blocks fully above output diagonal (masked downstream).
// vtOut/vtBase: blocks with n0 >= vtBase write output TRANSPOSED into vtOut[NB][DM][SEQ].
__global__ __launch_bounds__(256, 2) void gemm_bt(
    const unsigned short* __restrict__ A, int lda, long sA,
    const unsigned short* __restrict__ B, int ldb, long sB,
    void* __restrict__ Cv, int ldc, long sC,
    int K, const float* __restrict__ bias, float scale, int outf32, int trilskip,
    unsigned short* __restrict__ vtOut, int vtBase)
{
  const int m0 = blockIdx.x * 128, n0 = blockIdx.y * 128;
  if (trilskip && n0 > m0 + 127) return;
  __shared__ unsigned short As[128 * 64];
  __shared__ unsigned short Bs[128 * 64];
  const int tid = threadIdx.x;
  const int lane = tid & 63;
  const int wave = tid >> 6;
  const int wm = wave >> 1, wn = wave & 1;
  const unsigned short* Ab = A + (size_t)sA * blockIdx.z;
  const unsigned short* Bb = B + (size_t)sB * blockIdx.z;

  f32x4 acc[4][4];
#pragma unroll
  for (int i = 0; i < 4; ++i)
#pragma unroll
    for (int j = 0; j < 4; ++j)
      acc[i][j] = (f32x4){0.f, 0.f, 0.f, 0.f};

  const int nk = K >> 6;
  for (int kt = 0; kt < nk; ++kt) {
    __syncthreads();
    const int kb = kt << 6;
#pragma unroll
    for (int it = 0; it < 4; ++it) {
      int c = it * 256 + tid;
      int row = c >> 3;
      int lslot = (c & 7) ^ (row & 7);
      int ldsoff = (it * 256 + wave * 64) * 8;
      load_lds16(Ab + (size_t)(m0 + row) * lda + kb + lslot * 8, &As[ldsoff]);
      load_lds16(Bb + (size_t)(n0 + row) * ldb + kb + lslot * 8, &Bs[ldsoff]);
    }
    __syncthreads();
#pragma unroll
    for (int h = 0; h < 2; ++h) {
      bf16x8 af[4], bfr[4];
#pragma unroll
      for (int i = 0; i < 4; ++i) {
        int row = wm * 64 + i * 16 + (lane & 15);
        int pslot = (h * 4 + (lane >> 4)) ^ (row & 7);
        af[i] = *(const bf16x8*)&As[row * 64 + pslot * 8];
      }
#pragma unroll
      for (int j = 0; j < 4; ++j) {
        int row = wn * 64 + j * 16 + (lane & 15);
        int pslot = (h * 4 + (lane >> 4)) ^ (row & 7);
        bfr[j] = *(const bf16x8*)&Bs[row * 64 + pslot * 8];
      }
#pragma unroll
      for (int i = 0; i < 4; ++i)
#pragma unroll
        for (int j = 0; j < 4; ++j)
          acc[i][j] = __builtin_amdgcn_mfma_f32_16x16x32_bf16(af[i], bfr[j], acc[i][j], 0, 0, 0);
    }
  }

  // C/D layout: col = lane&15, row = (lane>>4)*4 + reg
  const int rsub = (lane >> 4) * 4;
  const int cbase = n0 + wn * 64 + (lane & 15);
  if (vtOut && n0 >= vtBase) {
    float bv[4] = {0.f, 0.f, 0.f, 0.f};
    if (bias) {
#pragma unroll
      for (int j = 0; j < 4; ++j) bv[j] = bias[cbase + j * 16];
    }
#pragma unroll
    for (int i = 0; i < 4; ++i) {
      int sg = m0 + wm * 64 + i * 16 + rsub;   // global row = batch*SEQ + s
      int bb = sg >> 11;
      int sl = sg & (SEQ - 1);
#pragma unroll
      for (int j = 0; j < 4; ++j) {
        int d = cbase + j * 16 - vtBase;
        u16x4 o;
#pragma unroll
        for (int r = 0; r < 4; ++r) o[r] = f2bf(acc[i][j][r] * scale + bv[j]);
        *(u16x4*)&vtOut[((size_t)bb * DM + d) * SEQ + sl] = o;
      }
    }
  } else if (outf32) {
    float* C = (float*)Cv + (size_t)sC * blockIdx.z;
#pragma unroll
    for (int i = 0; i < 4; ++i) {
      int rbase = m0 + wm * 64 + i * 16 + rsub;
#pragma unroll
      for (int j = 0; j < 4; ++j)
#pragma unroll
        for (int r = 0; r < 4; ++r)
          C[(size_t)(rbase + r) * ldc + cbase + j * 16] = acc[i][j][r] * scale;
    }
  } else {
    unsigned short* C = (unsigned short*)Cv + (size_t)sC * blockIdx.z;
    float bv[4] = {0.f, 0.f, 0.f, 0.f};
    if (bias) {
#pragma unroll
      for (int j = 0; j < 4; ++j) bv[j] = bias[cbase + j * 16];
    }
#pragma unroll
    for (int i = 0; i < 4; ++i) {
      int rbase = m0 + wm * 64 + i * 16 + rsub;
#pragma unroll
      for (int j = 0; j < 4; ++j)
#pragma unroll
        for (int r = 0; r < 4; ++r)
          C[(size_t)(rbase + r) * ldc + cbase + j * 16] = f2bf(acc[i][j][r] * scale + bv[j]);
    }
  }
}

// in-place row softmax over SEQ bf16 -> bf16 probs. one block per row.
__global__ __launch_bounds__(256) void softmax_kernel(unsigned short* __restrict__ Sc) {
  int row = blockIdx.x;
  int tid = threadIdx.x;
  unsigned short* sr = Sc + (size_t)row * SEQ;
  u16x8 raw = *(const u16x8*)&sr[tid * 8];
  float v[8];
#pragma unroll
  for (int j = 0; j < 8; ++j) v[j] = bf2f(raw[j]);
  float m = v[0];
#pragma unroll
  for (int j = 1; j < 8; ++j) m = fmaxf(m, v[j]);
#pragma unroll
  for (int off = 32; off; off >>= 1) m = fmaxf(m, __shfl_xor(m, off));
  __shared__ float red[8];
  int wv = tid >> 6;
  if ((tid & 63) == 0) red[wv] = m;
  __syncthreads();
  m = fmaxf(fmaxf(red[0], red[1]), fmaxf(red[2], red[3]));
  float s = 0.f;
#pragma unroll
  for (int j = 0; j < 8; ++j) { v[j] = __expf(v[j] - m); s += v[j]; }
#pragma unroll
  for (int off = 32; off; off >>= 1) s += __shfl_xor(s, off);
  if ((tid & 63) == 0) red[4 + wv] = s;
  __syncthreads();
  s = red[4] + red[5] + red[6] + red[7];
  float inv = 1.f / s;
  u16x8 o;
#pragma unroll
  for (int j = 0; j < 8; ++j) o[j] = f2bf(v[j] * inv);
  *(u16x8*)&sr[tid * 8] = o;
}

// y = LN(x + res(masked)) * g + b. x from f32 (xf) or bf16 (xb); out f32 or bf16.
__global__ __launch_bounds__(256) void ln_kernel(
    const float* __restrict__ xf, const unsigned short* __restrict__ xb,
    const unsigned short* __restrict__ res, int masked,
    const float* __restrict__ g, const float* __restrict__ be,
    float* __restrict__ outf, unsigned short* __restrict__ outb)
{
  int row = blockIdx.x;
  int s = row & (SEQ - 1);
  int tid = threadIdx.x;
  int d0 = tid * 4;
  float v[4];
  if (xf) {
    f32x4v t = ((const f32x4v*)(xf + (size_t)row * DM))[tid];
    v[0]=t[0]; v[1]=t[1]; v[2]=t[2]; v[3]=t[3];
  } else {
    u16x4 t = ((const u16x4*)(xb + (size_t)row * DM))[tid];
    v[0]=bf2f(t[0]); v[1]=bf2f(t[1]); v[2]=bf2f(t[2]); v[3]=bf2f(t[3]);
  }
  u16x4 rv = ((const u16x4*)(res + (size_t)row * DM))[tid];
#pragma unroll
  for (int j = 0; j < 4; ++j) {
    float r = bf2f(rv[j]);
    if (masked && (d0 + j) > s) r = 0.f;
    v[j] += r;
  }
  float s1 = v[0] + v[1] + v[2] + v[3];
  float s2 = v[0]*v[0] + v[1]*v[1] + v[2]*v[2] + v[3]*v[3];
#pragma unroll
  for (int off = 32; off; off >>= 1) { s1 += __shfl_xor(s1, off); s2 += __shfl_xor(s2, off); }
  __shared__ float red[8];
  int wv = tid >> 6;
  if ((tid & 63) == 0) { red[wv] = s1; red[4 + wv] = s2; }
  __syncthreads();
  s1 = red[0] + red[1] + red[2] + red[3];
  s2 = red[4] + red[5] + red[6] + red[7];
  float mean = s1 * (1.f / DM);
  float var = s2 * (1.f / DM) - mean * mean;
  float rstd = rsqrtf(var + 1e-5f);
  f32x4v gv = ((const f32x4v*)g)[tid];
  f32x4v bv = ((const f32x4v*)be)[tid];
  if (outf) {
    f32x4v o;
#pragma unroll
    for (int j = 0; j < 4; ++j) o[j] = (v[j] - mean) * rstd * gv[j] + bv[j];
    ((f32x4v*)(outf + (size_t)row * DM))[tid] = o;
  } else {
    u16x4 o;
#pragma unroll
    for (int j = 0; j < 4; ++j) o[j] = f2bf((v[j] - mean) * rstd * gv[j] + bv[j]);
    ((u16x4*)(outb + (size_t)row * DM))[tid] = o;
  }
}

extern "C" void kernel_launch(void* const* d_in, const int* in_sizes, int n_in,
                              void* d_out, int out_size, void* d_ws, size_t ws_size,
                              hipStream_t stream) {
  (void)in_sizes; (void)n_in; (void)out_size; (void)ws_size;
  const float* x     = (const float*)d_in[0];
  const float* wq_w  = (const float*)d_in[1];
  const float* wq_b  = (const float*)d_in[2];
  const float* wk_w  = (const float*)d_in[3];
  const float* wk_b  = (const float*)d_in[4];
  const float* wv_w  = (const float*)d_in[5];
  const float* wv_b  = (const float*)d_in[6];
  const float* lin_w = (const float*)d_in[7];
  const float* lin_b = (const float*)d_in[8];
  const float* g1    = (const float*)d_in[9];
  const float* b1    = (const float*)d_in[10];
  const float* g2    = (const float*)d_in[11];
  const float* b2    = (const float*)d_in[12];

  const size_t MB = 1ull << 20;
  char* ws = (char*)d_ws;
  // ---- workspace layout: NO overlays (peak 176 MiB) ----
  unsigned short* scP  = (unsigned short*)(ws);            // [0,32)   scores/probs bf16, in-place softmax
  unsigned short* attn = (unsigned short*)(ws + 32*MB);    // [32,48)
  unsigned short* x1   = (unsigned short*)(ws + 48*MB);    // [48,64)
  unsigned short* lin  = (unsigned short*)(ws + 64*MB);    // [64,80)
  unsigned short* xb   = (unsigned short*)(ws + 80*MB);    // [80,96)
  unsigned short* wqkvb= (unsigned short*)(ws + 96*MB);    // [96,102)
  unsigned short* lwb  = (unsigned short*)(ws + 102*MB);   // [102,104)
  float*          bqkv = (float*)(ws + 104*MB);            // [104,+12KiB)
  unsigned short* qkv  = (unsigned short*)(ws + 112*MB);   // [112,160)  (V cols unwritten/unused)
  unsigned short* vt   = (unsigned short*)(ws + 160*MB);   // [160,176)  V^T [NB][DM][SEQ]

  // 1. fused staging
  stage_kernel<<<2048, 256, 0, stream>>>(x, wq_w, wk_w, wv_w, lin_w, wq_b, wk_b, wv_b,
                                         xb, wqkvb, lwb, bqkv);

  // 2. fused QKV projection (64x24 = 1536 blocks); V blocks (n0>=2048) write V^T directly
  gemm_bt<<<dim3(64, 24, 1), 256, 0, stream>>>(xb, DM, 0, wqkvb, DM, 0, qkv, 3 * DM, 0,
                                               DM, bqkv, 1.f, 0, 0, vt, 2 * DM);

  const float scale = 0.03125f;  // 1/sqrt(1024)
  // 3. scores = (Q K^T) * scale -> bf16 (16x16x4 = 1024 blocks)
  gemm_bt<<<dim3(16, 16, NB), 256, 0, stream>>>(
      qkv, 3 * DM, (long)SEQ * 3 * DM,
      qkv + DM, 3 * DM, (long)SEQ * 3 * DM,
      scP, SEQ, (long)SEQ * SEQ, DM, nullptr, scale, 0, 0, nullptr, 0);
  // 4. softmax in-place
  softmax_kernel<<<NB * SEQ, 256, 0, stream>>>(scP);
  // 5. attn = P * (V^T)^T with tril tile-skip
  gemm_bt<<<dim3(16, 8, NB), 256, 0, stream>>>(
      scP, SEQ, (long)SEQ * SEQ,
      vt, SEQ, (long)DM * SEQ,
      attn, DM, (long)SEQ * DM, SEQ, nullptr, 1.f, 0, 1, nullptr, 0);

  // 6. LN1(xb + tril(attn)) -> x1 (bf16)
  ln_kernel<<<NB * SEQ, 256, 0, stream>>>(nullptr, xb, attn, 1, g1, b1, nullptr, x1);
  // 7. linear = x1 * lin_w^T + lin_b  (512 blocks)
  gemm_bt<<<dim3(64, 8, 1), 256, 0, stream>>>(x1, DM, 0, lwb, DM, 0, lin, DM, 0, DM,
                                              lin_b, 1.f, 0, 0, nullptr, 0);
  // 8. LN2(x1 + linear) -> d_out (f32)
  ln_kernel<<<NB * SEQ, 256, 0, stream>>>(nullptr, x1, lin, 0, g2, b2, (float*)d_out, nullptr);
}